// Round 1
// baseline (224.153 us; speedup 1.0000x reference)
//
#include <hip/hip_runtime.h>
#include <math.h>

// Problem constants (from reference)
constexpr int B_ = 32;
constexpr int N_ = 4096;
constexpr int H_ = 256;
constexpr int NNZ_ = 65536;

// ---------------------------------------------------------------------------
// 1. scatter validity mask: valid[b*N + n] = 1 for each nnz entry
// ---------------------------------------------------------------------------
__global__ void k_scatter(const int* __restrict__ bidx,
                          const int* __restrict__ ridx,
                          int* __restrict__ valid) {
    int k = blockIdx.x * 256 + threadIdx.x;
    if (k < NNZ_) {
        valid[bidx[k] * N_ + ridx[k]] = 1;
    }
}

// ---------------------------------------------------------------------------
// 2. per-batch root score: s2[b] = dot(x[b,0,:], W[H:2H])
// ---------------------------------------------------------------------------
__global__ void k_s2(const float* __restrict__ x,
                     const float* __restrict__ W,
                     float* __restrict__ s2) {
    int b = blockIdx.x;
    int t = threadIdx.x;  // 256 threads == H
    float v = x[(size_t)b * N_ * H_ + t] * W[H_ + t];
    __shared__ float red[256];
    red[t] = v;
    __syncthreads();
    for (int s = 128; s > 0; s >>= 1) {
        if (t < s) red[t] += red[t + s];
        __syncthreads();
    }
    if (t == 0) s2[b] = red[0];
}

// ---------------------------------------------------------------------------
// 3. scores: one wave (64 lanes) per (b,n) row. H=256 floats = 64 float4.
//    score = x[b,n]·W[:H] + bias + (valid ? s2[b] : 0)
//    val   = valid ? score : 0 ;  val==0 -> -inf   (matches reference quirk)
// ---------------------------------------------------------------------------
__global__ void k_scores(const float* __restrict__ x,
                         const float* __restrict__ W,
                         const float* __restrict__ s2,
                         const int* __restrict__ valid,
                         const float* __restrict__ bias,
                         float* __restrict__ scores) {
    int gtid = blockIdx.x * 256 + threadIdx.x;
    int row = gtid >> 6;          // global (b*N+n)
    int lane = threadIdx.x & 63;
    const float4 xv = ((const float4*)(x + (size_t)row * H_))[lane];
    const float4 wv = ((const float4*)W)[lane];
    float p = xv.x * wv.x + xv.y * wv.y + xv.z * wv.z + xv.w * wv.w;
    #pragma unroll
    for (int off = 32; off > 0; off >>= 1) p += __shfl_down(p, off, 64);
    if (lane == 0) {
        int b = row >> 12;  // N_ = 4096 = 2^12
        int vl = valid[row];
        float s = p + bias[0] + (vl ? s2[b] : 0.0f);
        float val = vl ? s : 0.0f;
        scores[row] = (val == 0.0f) ? -INFINITY : val;
    }
}

// ---------------------------------------------------------------------------
// 4. softmax over N per batch. One block of 1024 threads, 4 elems/thread.
//    Writes normalized attn directly into d_out's attn region.
// ---------------------------------------------------------------------------
__global__ void k_softmax(const float* __restrict__ scores,
                          float* __restrict__ attn) {
    int b = blockIdx.x;
    int t = threadIdx.x;
    int wave = t >> 6, lane = t & 63;
    const float* s = scores + (size_t)b * N_;

    float v[4];
    float m = -INFINITY;
    #pragma unroll
    for (int i = 0; i < 4; i++) {
        v[i] = s[t + i * 1024];
        m = fmaxf(m, v[i]);
    }
    #pragma unroll
    for (int off = 32; off > 0; off >>= 1) m = fmaxf(m, __shfl_xor(m, off, 64));

    __shared__ float red[16];
    __shared__ float bcast_m, bcast_z;
    if (lane == 0) red[wave] = m;
    __syncthreads();
    if (t == 0) {
        float mm = -INFINITY;
        for (int i = 0; i < 16; i++) mm = fmaxf(mm, red[i]);
        bcast_m = mm;
    }
    __syncthreads();
    m = bcast_m;

    float e[4];
    float sum = 0.0f;
    #pragma unroll
    for (int i = 0; i < 4; i++) {
        e[i] = (v[i] == -INFINITY) ? 0.0f : __expf(v[i] - m);
        sum += e[i];
    }
    #pragma unroll
    for (int off = 32; off > 0; off >>= 1) sum += __shfl_xor(sum, off, 64);
    if (lane == 0) red[wave] = sum;
    __syncthreads();
    if (t == 0) {
        float z = 0.0f;
        for (int i = 0; i < 16; i++) z += red[i];
        bcast_z = z;
    }
    __syncthreads();
    float inv = 1.0f / bcast_z;
    #pragma unroll
    for (int i = 0; i < 4; i++) {
        attn[(size_t)b * N_ + t + i * 1024] = e[i] * inv;
    }
}

// ---------------------------------------------------------------------------
// 5. out[b,h] = sum_n x[b,n,h] * attn[b,n]
//    grid (B, 32 chunks); each block does 128 n-rows, thread t owns h=t.
// ---------------------------------------------------------------------------
__global__ void k_out(const float* __restrict__ x,
                      const float* __restrict__ attn,
                      float* __restrict__ out) {
    int b = blockIdx.x;
    int c = blockIdx.y;
    int h = threadIdx.x;  // 256
    const float* xb = x + (size_t)b * N_ * H_;
    const float* ab = attn + (size_t)b * N_;
    int n0 = c * 128;

    __shared__ float a_s[128];
    if (h < 128) a_s[h] = ab[n0 + h];
    __syncthreads();

    float acc = 0.0f;
    for (int i = 0; i < 128; i++) {
        acc += xb[(size_t)(n0 + i) * H_ + h] * a_s[i];
    }
    atomicAdd(&out[b * H_ + h], acc);
}

// ---------------------------------------------------------------------------
extern "C" void kernel_launch(void* const* d_in, const int* in_sizes, int n_in,
                              void* d_out, int out_size, void* d_ws, size_t ws_size,
                              hipStream_t stream) {
    const float* x    = (const float*)d_in[0];
    const int*   bidx = (const int*)d_in[1];
    const int*   ridx = (const int*)d_in[2];
    const float* W    = (const float*)d_in[3];
    const float* bias = (const float*)d_in[4];

    float* out  = (float*)d_out;            // [B, H]
    float* attn = out + B_ * H_;            // [B, N] (the [B,N,1] output)

    int*   valid  = (int*)d_ws;                                   // B*N ints
    float* scores = (float*)((char*)d_ws + (size_t)B_ * N_ * 4);  // B*N floats
    float* s2     = scores + (size_t)B_ * N_;                     // B floats

    hipMemsetAsync(valid, 0, (size_t)B_ * N_ * sizeof(int), stream);
    hipMemsetAsync(out, 0, (size_t)B_ * H_ * sizeof(float), stream);

    k_scatter<<<NNZ_ / 256, 256, 0, stream>>>(bidx, ridx, valid);
    k_s2<<<B_, 256, 0, stream>>>(x, W, s2);
    k_scores<<<(B_ * N_) / 4, 256, 0, stream>>>(x, W, s2, valid, bias, scores);
    k_softmax<<<B_, 1024, 0, stream>>>(scores, attn);
    k_out<<<dim3(B_, 32), 256, 0, stream>>>(x, attn, out);
}